// Round 9
// baseline (253.874 us; speedup 1.0000x reference)
//
#include <hip/hip_runtime.h>
#include <hip/hip_bf16.h>
#include <math.h>

#define N_NODES 100000
#define F_IN    128
#define HC      128      // H*C
#define NH      4
#define SLOPE   0.2f

#define NB      196      // buckets = ceil(N/512)
#define BSH     9        // bucket = dst >> 9, local = dst & 511
#define CAP     10240    // per-bucket edge arena capacity (mean 8163, sigma ~90)
#define CAPC    10752    // per-bucket col arena (CAP + 512 self-loops)
#define CHUNK   2048     // edges per bucket block
#define CURPAD  16       // bucket_cursor stride in ints (64B: no false sharing)

typedef __attribute__((ext_vector_type(8))) short short8;   // bf16x8 MFMA frag
typedef __attribute__((ext_vector_type(4))) float f32x4;    // MFMA accum / native float4 (NT store ok)
typedef __attribute__((ext_vector_type(2))) float fx2;      // float2 for v_pk_fma_f32

static __device__ __forceinline__ float leaky(float x) { return x > 0.f ? x : SLOPE * x; }

static __device__ __forceinline__ short f2bs(float f) {
    __hip_bfloat16 b = __float2bfloat16(f);   // RTN-even
    return *reinterpret_cast<short*>(&b);
}

// unpack a bf16 pair (one u32) into a float2: lo -> .x, hi -> .y
static __device__ __forceinline__ fx2 bf2f2(unsigned int v) {
    fx2 r;
    r.x = __uint_as_float(v << 16);
    r.y = __uint_as_float(v & 0xffff0000u);
    return r;
}

// ---------------------------------------------------------------------------
// K0: one-time prep: wt = bf16 W^T; wab = folded attention vectors
// (a_src = x @ (W @ att_src) by linearity); zero bucket cursors.
// ---------------------------------------------------------------------------
__global__ __launch_bounds__(256) void k_pre(const float* __restrict__ W,
                                             const float* __restrict__ att_src,
                                             const float* __restrict__ att_dst,
                                             unsigned short* __restrict__ wt,
                                             unsigned short* __restrict__ wab,
                                             int* __restrict__ bucket_cursor)
{
    int t = blockIdx.x * 256 + threadIdx.x;
    if (t < 128 * 128) {
        int k = t >> 7, n = t & 127;
        wt[n * 128 + k] = (unsigned short)f2bs(W[k * HC + n]);
    } else if (t < 17408) {
        int i = t - 16384;
        int k = i >> 3, slot = i & 7;
        int head = slot & 3;
        const float* av = (slot & 4) ? att_dst : att_src;
        float dot = 0.f;
        #pragma unroll
        for (int c = 0; c < 32; ++c)
            dot += W[k * HC + head * 32 + c] * av[head * 32 + c];
        wab[slot * 128 + k] = (unsigned short)f2bs(dot);
    } else if (t < 18432) {
        int i = t - 17408;
        wab[(8 + (i >> 7)) * 128 + (i & 127)] = 0;
    }
    if (t < NB * CURPAD) bucket_cursor[t] = 0;
}

// ---------------------------------------------------------------------------
// K1: multisplit edges into NB dst-buckets via LDS staging; dense flushes.
// eb[bucket*CAP + k] = (src<<9) | (dst&511). 782 blocks. STANDALONE this
// round for profiling attribution.
// ---------------------------------------------------------------------------
__global__ __launch_bounds__(256) void k_bucket(const int* __restrict__ srcp,
                                                const int* __restrict__ dstp,
                                                int* __restrict__ bucket_cursor,
                                                int* __restrict__ eb, int E)
{
    __shared__ int ebuf[CHUNK];
    __shared__ unsigned char bkt[CHUNK];
    __shared__ int hist[256];
    __shared__ int lexcl[257];
    __shared__ int gbase[256];
    __shared__ int sdata[256];

    const int t = threadIdx.x;
    const int base = blockIdx.x * CHUNK;

    hist[t] = 0;
    __syncthreads();

    int sreg[8], dreg[8];
    #pragma unroll
    for (int j = 0; j < CHUNK / 256; ++j) {
        int i = base + t + j * 256;
        bool v = i < E;
        sreg[j] = v ? srcp[i] : 0;
        dreg[j] = v ? dstp[i] : -1;
        if (v) atomicAdd(&hist[dreg[j] >> BSH], 1);
    }
    __syncthreads();

    int cnt = hist[t];
    sdata[t] = cnt;
    __syncthreads();
    for (int o = 1; o < 256; o <<= 1) {
        int add = (t >= o) ? sdata[t - o] : 0;
        __syncthreads();
        sdata[t] += add;
        __syncthreads();
    }
    int excl = sdata[t] - cnt;
    lexcl[t] = excl;
    if (t == 255) lexcl[256] = sdata[255];
    hist[t] = excl;
    int gb = 0;
    if (t < NB && cnt > 0) gb = atomicAdd(&bucket_cursor[t * CURPAD], cnt);
    gbase[t] = t * CAP + gb;
    __syncthreads();

    #pragma unroll
    for (int j = 0; j < CHUNK / 256; ++j) {
        if (dreg[j] >= 0) {
            int b = dreg[j] >> BSH;
            int r = atomicAdd(&hist[b], 1);
            ebuf[r] = (sreg[j] << BSH) | (dreg[j] & 511);
            bkt[r] = (unsigned char)b;
        }
    }
    __syncthreads();

    const int blockTotal = lexcl[256];
    for (int i = t; i < blockTotal; i += 256) {
        int b = bkt[i];
        eb[gbase[b] + (i - lexcl[b])] = ebuf[i];
    }
}

// ---------------------------------------------------------------------------
// K2 (fused): blocks [0,NB) = per-bucket CSR (direct-global col writes, only
// 3KB LDS, hides under gemm); blocks [NB, +1563) = GEMM.
// GEMM is LDS-free on the input side: A-frags loaded directly from x
// (contiguous 32B per lane) + in-reg bf16 cvt; B-frags directly from the
// L2-resident 32KB wt. Output staged through a 16KB LDS buffer so hb is
// written with fully-coalesced 16B stores (was 32 scattered 2B stores).
// ---------------------------------------------------------------------------
union SMem {
    short ob[64 * 128];          // gemm output staging, 16 KB
    struct {
        int deg[512];
        int sdata[256];
    } c;                         // csr, 3 KB
};

__global__ __launch_bounds__(256) void k_fused(const float* __restrict__ x,
                                               const unsigned short* __restrict__ wt,
                                               const unsigned short* __restrict__ wab,
                                               unsigned short* __restrict__ hb,
                                               float* __restrict__ a_src,
                                               float* __restrict__ a_dst,
                                               const int* __restrict__ eb,
                                               const int* __restrict__ bucket_cursor,
                                               int* __restrict__ col,
                                               int2* __restrict__ rowse)
{
    __shared__ SMem sm;
    const int t = threadIdx.x;

    if (blockIdx.x < NB) {
        // ------------------------- per-bucket CSR -------------------------
        const int b  = blockIdx.x;
        const int n0 = b * 512;
        const int cnt   = bucket_cursor[b * CURPAD];
        const int ebase = b * CAP;
        const int gofs  = b * CAPC;
        const int nvalid = min(512, N_NODES - n0);

        sm.c.deg[t]       = (t       < nvalid) ? 1 : 0;
        sm.c.deg[t + 256] = (t + 256 < nvalid) ? 1 : 0;
        __syncthreads();

        for (int i = t; i < cnt; i += 256)
            atomicAdd(&sm.c.deg[eb[ebase + i] & 511], 1);
        __syncthreads();

        int d0 = sm.c.deg[2 * t], d1 = sm.c.deg[2 * t + 1];
        int ps = d0 + d1;
        sm.c.sdata[t] = ps;
        __syncthreads();
        for (int o = 1; o < 256; o <<= 1) {
            int add = (t >= o) ? sm.c.sdata[t - o] : 0;
            __syncthreads();
            sm.c.sdata[t] += add;
            __syncthreads();
        }
        int e0 = sm.c.sdata[t] - ps;
        int e1 = e0 + d0;
        __syncthreads();

        int na = n0 + 2 * t, nb2 = n0 + 2 * t + 1;
        if (na < N_NODES) {
            rowse[na] = make_int2(gofs + e0, gofs + e0 + d0);
            col[gofs + e0] = na;
        }
        if (nb2 < N_NODES) {
            rowse[nb2] = make_int2(gofs + e1, gofs + e1 + d1);
            col[gofs + e1] = nb2;
        }
        sm.c.deg[2 * t]     = e0 + 1;
        sm.c.deg[2 * t + 1] = e1 + 1;
        __syncthreads();

        for (int i = t; i < cnt; i += 256) {
            int v = eb[ebase + i];
            int r = atomicAdd(&sm.c.deg[v & 511], 1);
            col[gofs + r] = v >> BSH;
        }
        // zero the prefetch tail (k_node reads up to top+47 ahead)
        const int top = cnt + nvalid;
        const int upper = min(CAPC, (top + 64 + 15) & ~15);
        for (int i = top + t; i < upper; i += 256) col[gofs + i] = 0;
    } else {
        // ------------------------------ GEMM ------------------------------
        const int r0 = (blockIdx.x - NB) * 64;
        const int wave = t >> 6, lane = t & 63;
        const int quad = lane >> 4, l16 = lane & 15;
        const int wrow = wave * 16;

        const int grow = r0 + wrow + l16;                 // A-frag row
        const int xrow = min(grow, N_NODES - 1);
        const float* xp = x + (size_t)xrow * F_IN;

        f32x4 acc[8];
        #pragma unroll
        for (int nt = 0; nt < 8; ++nt) acc[nt] = (f32x4){0.f, 0.f, 0.f, 0.f};
        f32x4 acca = (f32x4){0.f, 0.f, 0.f, 0.f};

        #pragma unroll
        for (int kb = 0; kb < 4; ++kb) {
            float4 xa = *(const float4*)&xp[kb * 32 + quad * 8];
            float4 xb = *(const float4*)&xp[kb * 32 + quad * 8 + 4];
            short8 a;
            a[0] = f2bs(xa.x); a[1] = f2bs(xa.y); a[2] = f2bs(xa.z); a[3] = f2bs(xa.w);
            a[4] = f2bs(xb.x); a[5] = f2bs(xb.y); a[6] = f2bs(xb.z); a[7] = f2bs(xb.w);
            #pragma unroll
            for (int nt = 0; nt < 8; ++nt) {
                short8 b = *(const short8*)&wt[(nt * 16 + l16) * 128 + kb * 32 + quad * 8];
                acc[nt] = __builtin_amdgcn_mfma_f32_16x16x32_bf16(a, b, acc[nt], 0, 0, 0);
            }
            short8 bwa = *(const short8*)&wab[l16 * 128 + kb * 32 + quad * 8];
            acca = __builtin_amdgcn_mfma_f32_16x16x32_bf16(a, bwa, acca, 0, 0, 0);
        }

        // stage output tile in LDS (bf16), plus a-scalar stores
        #pragma unroll
        for (int g = 0; g < 4; ++g) {
            int lrow = wrow + quad * 4 + g;
            int r = r0 + lrow;
            #pragma unroll
            for (int nt = 0; nt < 8; ++nt)
                sm.ob[lrow * 128 + nt * 16 + l16] = f2bs(acc[nt][g]);
            if (r < N_NODES) {
                if (l16 < 4)      a_src[r * NH + l16]       = acca[g];
                else if (l16 < 8) a_dst[r * NH + (l16 - 4)] = acca[g];
            }
        }
        __syncthreads();

        // coalesced flush: 1024 int4 chunks; instruction i covers chunks
        // [i*256, i*256+256) -> consecutive 16B across the block
        const int4* s4 = (const int4*)sm.ob;
        #pragma unroll
        for (int i = 0; i < 4; ++i) {
            int c = i * 256 + t;
            int row = c >> 4;
            int r = r0 + row;
            if (r < N_NODES)
                *(int4*)&hb[(size_t)r * HC + (c & 15) * 8] = s4[c];
        }
    }
}

// ---------------------------------------------------------------------------
// K3: per-dst-node softmax + aggregation. 16-lane groups own edges; 4-deep
// GUARD-FREE pipeline (16 edges/iter, 4 gathers in flight per lane; col tail
// zero-filled to top+64 by csr). Packed float2 FMAs.
// ---------------------------------------------------------------------------
__global__ __launch_bounds__(256) void k_node(const unsigned short* __restrict__ hb,
                                              const float* __restrict__ a_src,
                                              const float* __restrict__ a_dst,
                                              const int2* __restrict__ rowse,
                                              const int* __restrict__ col,
                                              const float* __restrict__ bias,
                                              float* __restrict__ out)
{
    const int lane = threadIdx.x & 63;
    const int node = blockIdx.x * 4 + (threadIdx.x >> 6);
    if (node >= N_NODES) return;

    const int g   = lane >> 4;   // edge slot within wave
    const int l16 = lane & 15;   // 16B slice within 256B row
    const int myh = l16 >> 2;    // head of my 8 elements

    const int2 se = rowse[node];
    const int r0 = se.x;
    const int cnt = se.y - se.x;

    const float adm = a_dst[node * NH + myh];

    fx2 acc2[4];
    #pragma unroll
    for (int k = 0; k < 4; ++k) acc2[k] = (fx2){0.f, 0.f};
    float denom = 0.f;

    #define HROW(c) (((const uint4*)(hb + (size_t)(c) * HC))[l16])

    // prologue: 4 edges' gathers in flight + next 4 cols
    int   c0 = col[r0 + g],      c1 = col[r0 + 4 + g];
    int   c2 = col[r0 + 8 + g],  c3 = col[r0 + 12 + g];
    float a0 = a_src[c0 * NH + myh], a1 = a_src[c1 * NH + myh];
    float a2 = a_src[c2 * NH + myh], a3 = a_src[c3 * NH + myh];
    uint4 h0 = HROW(c0), h1 = HROW(c1), h2 = HROW(c2), h3 = HROW(c3);
    int   n0 = col[r0 + 16 + g], n1 = col[r0 + 20 + g];
    int   n2 = col[r0 + 24 + g], n3 = col[r0 + 28 + g];

    for (int i = 0; i < cnt; i += 16) {
        // gathers for iter i+16
        float b0 = a_src[n0 * NH + myh], b1 = a_src[n1 * NH + myh];
        float b2 = a_src[n2 * NH + myh], b3 = a_src[n3 * NH + myh];
        uint4 j0 = HROW(n0), j1 = HROW(n1), j2 = HROW(n2), j3 = HROW(n3);
        // cols for iter i+32 (max idx r0+cnt+46 < zero-tail bound)
        int m0 = col[r0 + i + 32 + g], m1 = col[r0 + i + 36 + g];
        int m2 = col[r0 + i + 40 + g], m3 = col[r0 + i + 44 + g];

        // compute iter i: only p is masked
        float p0 = (i + g      < cnt) ? __expf(leaky(a0 + adm)) : 0.f;
        float p1 = (i + 4 + g  < cnt) ? __expf(leaky(a1 + adm)) : 0.f;
        float p2 = (i + 8 + g  < cnt) ? __expf(leaky(a2 + adm)) : 0.f;
        float p3 = (i + 12 + g < cnt) ? __expf(leaky(a3 + adm)) : 0.f;
        denom += (p0 + p1) + (p2 + p3);
        fx2 q0 = (fx2){p0, p0}, q1 = (fx2){p1, p1};
        fx2 q2 = (fx2){p2, p2}, q3 = (fx2){p3, p3};
        acc2[0] = __builtin_elementwise_fma(bf2f2(h0.x), q0, acc2[0]);
        acc2[0] = __builtin_elementwise_fma(bf2f2(h1.x), q1, acc2[0]);
        acc2[0] = __builtin_elementwise_fma(bf2f2(h2.x), q2, acc2[0]);
        acc2[0] = __builtin_elementwise_fma(bf2f2(h3.x), q3, acc2[0]);
        acc2[1] = __builtin_elementwise_fma(bf2f2(h0.y), q0, acc2[1]);
        acc2[1] = __builtin_elementwise_fma(bf2f2(h1.y), q1, acc2[1]);
        acc2[1] = __builtin_elementwise_fma(bf2f2(h2.y), q2, acc2[1]);
        acc2[1] = __builtin_elementwise_fma(bf2f2(h3.y), q3, acc2[1]);
        acc2[2] = __builtin_elementwise_fma(bf2f2(h0.z), q0, acc2[2]);
        acc2[2] = __builtin_elementwise_fma(bf2f2(h1.z), q1, acc2[2]);
        acc2[2] = __builtin_elementwise_fma(bf2f2(h2.z), q2, acc2[2]);
        acc2[2] = __builtin_elementwise_fma(bf2f2(h3.z), q3, acc2[2]);
        acc2[3] = __builtin_elementwise_fma(bf2f2(h0.w), q0, acc2[3]);
        acc2[3] = __builtin_elementwise_fma(bf2f2(h1.w), q1, acc2[3]);
        acc2[3] = __builtin_elementwise_fma(bf2f2(h2.w), q2, acc2[3]);
        acc2[3] = __builtin_elementwise_fma(bf2f2(h3.w), q3, acc2[3]);

        // rotate pipeline
        a0 = b0; a1 = b1; a2 = b2; a3 = b3;
        h0 = j0; h1 = j1; h2 = j2; h3 = j3;
        n0 = m0; n1 = m1; n2 = m2; n3 = m3;
    }
    #undef HROW

    // reduce the 4 edge-groups: lanes l, l^16, l^32, l^48 hold the same slice
    #pragma unroll
    for (int o = 16; o < 64; o <<= 1) {
        denom += __shfl_xor(denom, o);
        #pragma unroll
        for (int k = 0; k < 4; ++k) {
            acc2[k].x += __shfl_xor(acc2[k].x, o);
            acc2[k].y += __shfl_xor(acc2[k].y, o);
        }
    }

    if (g == 0) {
        float inv = 1.f / (denom + 1e-16f);
        const float* bp = &bias[l16 * 8];
        f32x4 o0, o1;
        o0.x = acc2[0].x * inv + bp[0]; o0.y = acc2[0].y * inv + bp[1];
        o0.z = acc2[1].x * inv + bp[2]; o0.w = acc2[1].y * inv + bp[3];
        o1.x = acc2[2].x * inv + bp[4]; o1.y = acc2[2].y * inv + bp[5];
        o1.z = acc2[3].x * inv + bp[6]; o1.w = acc2[3].y * inv + bp[7];
        __builtin_nontemporal_store(o0, (f32x4*)&out[(size_t)node * HC + l16 * 8]);
        __builtin_nontemporal_store(o1, (f32x4*)&out[(size_t)node * HC + l16 * 8 + 4]);
    }
}

// ---------------------------------------------------------------------------
extern "C" void kernel_launch(void* const* d_in, const int* in_sizes, int n_in,
                              void* d_out, int out_size, void* d_ws, size_t ws_size,
                              hipStream_t stream)
{
    const float* x       = (const float*)d_in[0];
    const float* W       = (const float*)d_in[1];
    const float* att_src = (const float*)d_in[2];
    const float* att_dst = (const float*)d_in[3];
    const float* bias    = (const float*)d_in[4];
    const int*   ei      = (const int*)d_in[5];
    const int E = in_sizes[5] / 2;
    const int* srcp = ei;
    const int* dstp = ei + E;
    float* out = (float*)d_out;

    char* wsb = (char*)d_ws;
    size_t off = 0;
    auto alloc = [&](size_t bytes) -> char* {
        char* p = wsb + off;
        off += (bytes + 255) & ~(size_t)255;
        return p;
    };
    unsigned short* hb = (unsigned short*)alloc((size_t)N_NODES * HC * sizeof(unsigned short)); // 25.6 MB
    float* a_src   = (float*)alloc((size_t)N_NODES * NH * sizeof(float));
    float* a_dst   = (float*)alloc((size_t)N_NODES * NH * sizeof(float));
    int*   eb      = (int*)alloc((size_t)NB * CAP * sizeof(int));          // 8.0 MB
    int*   col     = (int*)alloc((size_t)NB * CAPC * sizeof(int));         // 8.4 MB
    int2*  rowse   = (int2*)alloc((size_t)N_NODES * sizeof(int2));         // 0.8 MB
    int*   bcursor = (int*)alloc((size_t)NB * CURPAD * sizeof(int));       // 12.5 KB padded
    unsigned short* wt  = (unsigned short*)alloc(128 * 128 * sizeof(unsigned short));
    unsigned short* wab = (unsigned short*)alloc(16 * 128 * sizeof(unsigned short)); // 4 KB

    const int bucketBlocks = (E + CHUNK - 1) / CHUNK;
    const int gemmBlocks   = (N_NODES + 63) / 64;

    k_pre<<<73, 256, 0, stream>>>(W, att_src, att_dst, wt, wab, bcursor);
    k_bucket<<<bucketBlocks, 256, 0, stream>>>(srcp, dstp, bcursor, eb, E);
    k_fused<<<NB + gemmBlocks, 256, 0, stream>>>(x, wt, wab, hb, a_src, a_dst,
                                                 eb, bcursor, col, rowse);
    k_node<<<(N_NODES + 3) / 4, 256, 0, stream>>>(hb, a_src, a_dst, rowse, col, bias, out);
}